// Round 1
// 198.113 us; speedup vs baseline: 1.0070x; 1.0070x over previous
//
#include <hip/hip_runtime.h>

// CARAFE++ (B=4, C=256, H=W=64, SCALE=2, K=5, G=1, MID=64, ENC_OUT=100). FP32 I/O.
// R6: 199us; enc 64us @ 19.7% occupancy (grid 256 x 512thr = 2 waves/SIMD,
//     VALUBusy 23% -> latency-bound).
// R7: enc -> 1024 thr = 64 px x 16 groups (q=7 outputs each), g=t>>6 stays
//     wave-uniform so weights remain scalar loads. 16 waves/CU (50% occ).
//     Predicted enc ~25-30us (new floor: LDS pipe ~22us/CU).
//
// ws layout (float offsets):
#define OFF_FEAT 0              // feat [b][m][4096]               1,048,576 f
#define OFF_WET  1048576        // W_enc^T [m*9+rs][p*28+k pad]       64,512 f
#define OFF_WCT  1113088        // W_comp^T [c][m]                    16,384 f
#define OFF_WK   1129472        // wk2 [p*25+k][b*4096+pix]        1,638,400 f
#define WS_FLOATS 2767872       // = 11,071,488 bytes

// ---------------- prep: weight transposes ----------------
__global__ __launch_bounds__(256) void prep_kernel(
    const float* __restrict__ Wc, const float* __restrict__ We,
    float* __restrict__ ws) {
    int i = blockIdx.x * 256 + threadIdx.x;
    if (i < 16384) {                       // WcT[c*64+m] = Wc[m][c]
        int c = i >> 6, m = i & 63;
        ws[OFF_WCT + i] = Wc[m * 256 + c];
    }
    if (i < 64512) {                       // Wet[(m*9+rs)*112 + p*28 + kk]
        int mrs = i / 112, rem = i - mrs * 112;
        int p = rem / 28, kk = rem - p * 28;
        ws[OFF_WET + i] = (kk < 25) ? We[(p * 25 + kk) * 576 + mrs] : 0.f;
    }
}

// ---------------- K1: 1x1 compress conv + relu ----------------
// grid 1024 = 256 px-groups x 4 m-quarters. 256 thr = 64 lanes x 4 chunks(4 m).
// 4 staging phases of 64 ch (16 KB LDS) -> more blocks/CU than R5's 32 KB.
__global__ __launch_bounds__(256) void compress_kernel(
    const float* __restrict__ x, const float* __restrict__ bc,
    const float* __restrict__ ws, float* __restrict__ feat) {
    __shared__ float xs[64 * 64];          // 16 KB
    int blk = blockIdx.x;
    int pxg = blk >> 2, mq = blk & 3;
    int pixbase = pxg * 64;
    int b = pixbase >> 12, pl = pixbase & 4095;
    int lane = threadIdx.x & 63;
    int chunk = __builtin_amdgcn_readfirstlane(threadIdx.x >> 6);
    int m0 = mq * 16 + chunk * 4;          // wave-uniform
    const float* wct = ws + OFF_WCT;
    float acc[4];
#pragma unroll
    for (int q = 0; q < 4; q++) acc[q] = 0.f;
    for (int h = 0; h < 4; h++) {
        int ch0 = h << 6;
        for (int idx = threadIdx.x; idx < 64 * 64; idx += 256) {
            int c = idx >> 6, pp = idx & 63;
            xs[idx] = x[((b * 256 + ch0 + c) << 12) + pl + pp];
        }
        __syncthreads();
        for (int c = 0; c < 64; c++) {
            float xv = xs[(c << 6) + lane];
            const float* wr = wct + (ch0 + c) * 64 + m0;   // uniform -> s_load
#pragma unroll
            for (int q = 0; q < 4; q++) acc[q] += xv * wr[q];
        }
        __syncthreads();
    }
#pragma unroll
    for (int q = 0; q < 4; q++) {
        int m = m0 + q;
        float v = acc[q] + bc[m];
        feat[(b * 64 + m) * 4096 + pl + lane] = v > 0.f ? v : 0.f;
    }
}

// ---------------- K2: 3x3 enc conv + bias + softmax(25) ----------------
// grid 256 (b x 8x8 tile), 1024 thr = 64 px x (4 p x 4 k-quarters), q=7.
// Weights via wave-uniform scalar loads (no LDS staging, 3 barriers total).
// 16 waves/block, 1 block/CU -> 4 waves/SIMD (50% occupancy).
__global__ __launch_bounds__(1024) void enc_kernel(
    const float* __restrict__ be, const float* __restrict__ ws,
    float* __restrict__ wkout) {
    __shared__ float fs[6400];             // feat halo [m][10x10] / later logits [px][100]
    int t = threadIdx.x;
    int blk = blockIdx.x;
    int b = blk >> 6, tile = blk & 63;
    int i0 = (tile >> 3) << 3, j0 = (tile & 7) << 3;
    int pix = t & 63;
    int li = pix >> 3, lj = pix & 7;
    int g = __builtin_amdgcn_readfirstlane(t >> 6);  // 0..15, wave-uniform
    int p = g >> 2, k0 = (g & 3) * 7;                // kk = k0 + q, 0..27 (pad >=25)
    const float* feat = ws + OFF_FEAT;
    const float* wet = ws + OFF_WET + p * 28 + k0;   // uniform base

    for (int idx = t; idx < 6400; idx += 1024) {     // stage feat halo (0-padded)
        int m = idx / 100, pos = idx - m * 100;
        int r = pos / 10, s = pos - r * 10;
        int gi = i0 + r - 1, gj = j0 + s - 1;
        float v = 0.f;
        if ((unsigned)gi < 64u && (unsigned)gj < 64u)
            v = feat[(b * 64 + m) * 4096 + (gi << 6) + gj];
        fs[idx] = v;
    }
    __syncthreads();

    float acc[7];
#pragma unroll
    for (int q = 0; q < 7; q++) acc[q] = 0.f;

    for (int m = 0; m < 64; m++) {
        const float* fb = fs + m * 100 + li * 10 + lj;
        float f9[9];
#pragma unroll
        for (int r = 0; r < 3; r++)
#pragma unroll
            for (int s = 0; s < 3; s++) f9[r * 3 + s] = fb[r * 10 + s];
        const float* wrow = wet + m * 9 * 112;       // uniform -> s_load_dwordx
#pragma unroll
        for (int rs = 0; rs < 9; rs++) {
            float f = f9[rs];
            const float* wr = wrow + rs * 112;
#pragma unroll
            for (int q = 0; q < 7; q++) acc[q] += f * wr[q];
        }
    }
    __syncthreads();                                 // halo reads done

    // logits (+bias) -> fs[pix*100 + p*25 + kk] (kk>=25 is pad, skip)
#pragma unroll
    for (int q = 0; q < 7; q++) {
        int k = k0 + q;
        if (k < 25) fs[pix * 100 + p * 25 + k] = acc[q] + be[p * 25 + k];
    }
    __syncthreads();

    if (t < 256) {                                   // softmax: thread = (pix, p)
        int sp = t >> 6, spx = t & 63;
        const float* lg = fs + spx * 100 + sp * 25;
        float sv[25], mx = -1e30f;
#pragma unroll
        for (int k = 0; k < 25; k++) { sv[k] = lg[k]; mx = fmaxf(mx, sv[k]); }
        float s = 0.f;
#pragma unroll
        for (int k = 0; k < 25; k++) { sv[k] = __expf(sv[k] - mx); s += sv[k]; }
        float inv = 1.f / s;
        int pgl = ((i0 + (spx >> 3)) << 6) + j0 + (spx & 7);
        float* wp = wkout + (sp * 25) * 16384 + (b << 12) + pgl;
#pragma unroll
        for (int k = 0; k < 25; k++) wp[k * 16384] = sv[k] * inv;  // coalesced
    }
}

// ---------------- K3: gather + pixel rearrange ----------------
// grid 4096 = (b*64+i)*16 + cc(16 ch). 256 thr = 64 j x (2 p-pairs x 2 c-halves).
// LDS 21.8 KB -> 7 blocks/CU (28 waves) vs R5's 3 (12 waves).
__global__ __launch_bounds__(256) void gather_kernel(
    const float* __restrict__ x, const float* __restrict__ ws,
    float* __restrict__ out) {
    __shared__ float xs[16 * 5 * 68];                // 21.76 KB
    int t = threadIdx.x;
    int blk = blockIdx.x;
    int cc = blk & 15;
    int bi = blk >> 4;
    int b = bi >> 6, i = bi & 63;
    int j = t & 63;
    int g = t >> 6;
    int ph = g >> 1, ch = g & 1;

    // coalesced wk loads: wk2[(p*25+k)*16384 + b*4096 + i*64 + j]
    float w0[25], w1[25];
    {
        const float* wp = ws + OFF_WK + (ph * 50) * 16384 + (b << 12) + (i << 6) + j;
#pragma unroll
        for (int k = 0; k < 25; k++) {
            w0[k] = wp[k * 16384];
            w1[k] = wp[(25 + k) * 16384];
        }
    }

    // div-free-ish staging: aligned 64-float row core + guarded zero pads.
    {
        int lane = t & 63, cd0 = t >> 6;             // (c,dy) pairs, 4 at a time
        for (int cd = cd0; cd < 80; cd += 4) {
            int c = cd / 5, dy = cd - c * 5;
            int gi = i - 2 + dy;
            float v = 0.f;
            if ((unsigned)gi < 64u)
                v = x[((b * 256 + (cc << 4) + c) << 12) + (gi << 6) + lane];
            float* row = xs + cd * 68;
            row[2 + lane] = v;
            if (lane < 2) row[lane] = 0.f;           // gj < 0 pad
            if (lane >= 62) row[lane + 4] = 0.f;     // gj >= 64 pad
        }
    }
    __syncthreads();

    for (int c2 = ch; c2 < 16; c2 += 2) {
        const float* xb = xs + (c2 * 5) * 68 + j;    // u = j+dx -> gj = j+dx-2
        float a0 = 0.f, a1 = 0.f;
#pragma unroll
        for (int dy = 0; dy < 5; dy++) {
#pragma unroll
            for (int dx = 0; dx < 5; dx++) {
                float xv = xb[dy * 68 + dx];
                int k = dy * 5 + dx;
                a0 += xv * w0[k];
                a1 += xv * w1[k];
            }
        }
        int c = (cc << 4) + c2;
        float2 o2 = make_float2(a0, a1);
        *(float2*)(out + (((b * 256 + c) << 12) + (i << 6) + j) * 4 + ph * 2) = o2;
    }
}

// ---------------- fallback: round-3 fused kernel (correct, slow) ----------------
__global__ __launch_bounds__(512) void carafe_fused(
    const float* __restrict__ x, const float* __restrict__ Wc,
    const float* __restrict__ bc, const float* __restrict__ We,
    const float* __restrict__ be, float* __restrict__ out) {
    __shared__ float xs[32 * 144];
    __shared__ float fw[6656];
    __shared__ float wst[3600];
    const int t = threadIdx.x;
    const int blk = blockIdx.x;
    const int b = blk >> 6, tile = blk & 63;
    const int i0 = (tile >> 3) << 3, j0 = (tile & 7) << 3;
    const int wid = t >> 6, pix = t & 63;
    const int li = pix >> 3, lj = pix & 7;
    float facc[13];
#pragma unroll
    for (int q = 0; q < 13; q++) facc[q] = 0.f;
    for (int cc = 0; cc < 8; cc++) {
        for (int idx = t; idx < 32 * 144; idx += 512) {
            int c = idx / 144, pos = idx - c * 144;
            int r = pos / 12, u = pos - r * 12;
            int gi = i0 + r - 2, gj = j0 + u - 2;
            float v = 0.f;
            if ((unsigned)gi < 64u && (unsigned)gj < 64u)
                v = x[(((b * 256 + cc * 32 + c) << 12) + (gi << 6) + gj)];
            xs[idx] = v;
        }
        __syncthreads();
#pragma unroll
        for (int q = 0; q < 13; q++) {
            int idx = q * 512 + t;
            if (idx < 6400) {
                int m = idx / 100, pos = idx - m * 100;
                int fi = pos / 10, fj = pos - fi * 10;
                int tp = (fi + 1) * 12 + fj + 1;
                const float* wr = Wc + m * 256 + cc * 32;
                float a = facc[q];
                for (int c = 0; c < 32; c++) a += xs[c * 144 + tp] * wr[c];
                facc[q] = a;
            }
        }
        __syncthreads();
    }
#pragma unroll
    for (int q = 0; q < 13; q++) {
        int idx = q * 512 + t;
        if (idx < 6400) {
            int m = idx / 100, pos = idx - m * 100;
            int fi = pos / 10, fj = pos - fi * 10;
            int gi = i0 + fi - 1, gj = j0 + fj - 1;
            float v = facc[q] + bc[m];
            v = v > 0.f ? v : 0.f;
            if ((unsigned)gi >= 64u || (unsigned)gj >= 64u) v = 0.f;
            fw[idx] = v;
        }
    }
    float acc[13];
#pragma unroll
    for (int q = 0; q < 13; q++) acc[q] = 0.f;
    for (int mb = 0; mb < 16; mb++) {
        for (int idx = t; idx < 3600; idx += 512) {
            int mm = idx / 900, rem = idx - mm * 900;
            int o = rem / 9, rs = rem - o * 9;
            wst[idx] = We[o * 576 + (mb * 4 + mm) * 9 + rs];
        }
        __syncthreads();
#pragma unroll
        for (int mm = 0; mm < 4; mm++) {
            const float* fb = fw + (mb * 4 + mm) * 100 + li * 10 + lj;
            float f9[9];
#pragma unroll
            for (int r = 0; r < 3; r++)
#pragma unroll
                for (int s = 0; s < 3; s++) f9[r * 3 + s] = fb[r * 10 + s];
#pragma unroll
            for (int q = 0; q < 13; q++) {
                int o = q * 8 + wid;
                if (o < 100) {
                    const float* wr = wst + mm * 900 + o * 9;
                    float a = acc[q];
#pragma unroll
                    for (int rs = 0; rs < 9; rs++) a += f9[rs] * wr[rs];
                    acc[q] = a;
                }
            }
        }
        __syncthreads();
    }
#pragma unroll
    for (int q = 0; q < 13; q++) {
        int o = q * 8 + wid;
        if (o < 100) fw[pix * 104 + o] = acc[q];
    }
    __syncthreads();
    float sv[25];
    float inv = 0.f;
    const int sp = t >> 6, spx = t & 63;
    const bool act = (t < 256);
    if (act) {
        float mx = -1e30f;
#pragma unroll
        for (int k = 0; k < 25; k++) {
            sv[k] = fw[spx * 104 + sp * 25 + k] + be[sp * 25 + k];
            mx = fmaxf(mx, sv[k]);
        }
        float s = 0.f;
#pragma unroll
        for (int k = 0; k < 25; k++) { sv[k] = __expf(sv[k] - mx); s += sv[k]; }
        inv = 1.f / s;
    }
    __syncthreads();
    if (act) {
#pragma unroll
        for (int k = 0; k < 25; k++) fw[spx * 104 + k * 4 + sp] = sv[k] * inv;
    }
    __syncthreads();
    float w[25][4];
    const float4* wp = (const float4*)(fw + pix * 104);
#pragma unroll
    for (int k = 0; k < 25; k++) {
        float4 ww = wp[k];
        w[k][0] = ww.x; w[k][1] = ww.y; w[k][2] = ww.z; w[k][3] = ww.w;
    }
    const int pgl = ((i0 + li) << 6) + (j0 + lj);
    for (int cc = 0; cc < 8; cc++) {
        for (int idx = t; idx < 32 * 144; idx += 512) {
            int c = idx / 144, pos = idx - c * 144;
            int r = pos / 12, u = pos - r * 12;
            int gi = i0 + r - 2, gj = j0 + u - 2;
            float v = 0.f;
            if ((unsigned)gi < 64u && (unsigned)gj < 64u)
                v = x[(((b * 256 + cc * 32 + c) << 12) + (gi << 6) + gj)];
            xs[idx] = v;
        }
        __syncthreads();
        for (int c8 = wid; c8 < 32; c8 += 8) {
            const float* xc = xs + c8 * 144 + li * 12 + lj;
            float a0 = 0.f, a1 = 0.f, a2 = 0.f, a3 = 0.f;
#pragma unroll
            for (int dy = 0; dy < 5; dy++) {
#pragma unroll
                for (int dx = 0; dx < 5; dx++) {
                    float xv = xc[dy * 12 + dx];
                    const int k = dy * 5 + dx;
                    a0 += xv * w[k][0];
                    a1 += xv * w[k][1];
                    a2 += xv * w[k][2];
                    a3 += xv * w[k][3];
                }
            }
            int c = cc * 32 + c8;
            float4 o4 = make_float4(a0, a1, a2, a3);
            *(float4*)(out + (((long long)(b * 256 + c)) << 14) + pgl * 4) = o4;
        }
        __syncthreads();
    }
}

extern "C" void kernel_launch(void* const* d_in, const int* in_sizes, int n_in,
                              void* d_out, int out_size, void* d_ws, size_t ws_size,
                              hipStream_t stream) {
    const float* x  = (const float*)d_in[0];
    const float* Wc = (const float*)d_in[1];
    const float* bc = (const float*)d_in[2];
    const float* We = (const float*)d_in[3];
    const float* be = (const float*)d_in[4];
    float* out = (float*)d_out;

    if (ws_size >= (size_t)WS_FLOATS * sizeof(float)) {
        float* ws = (float*)d_ws;
        prep_kernel<<<252, 256, 0, stream>>>(Wc, We, ws);
        compress_kernel<<<1024, 256, 0, stream>>>(x, bc, ws, ws + OFF_FEAT);
        enc_kernel<<<256, 1024, 0, stream>>>(be, ws, ws + OFF_WK);
        gather_kernel<<<4096, 256, 0, stream>>>(x, ws, out);
    } else {
        carafe_fused<<<256, 512, 0, stream>>>(x, Wc, bc, We, be, out);
    }
}

// Round 2
// 192.675 us; speedup vs baseline: 1.0354x; 1.0282x over previous
//
#include <hip/hip_runtime.h>

// CARAFE++ (B=4, C=256, H=W=64, SCALE=2, K=5, G=1, MID=64, ENC_OUT=100). FP32 I/O.
// R7: 198us; enc 59us @ 39% occ, VALUBusy 32% -> NOT latency-bound; weight path
//     is ~63 fragmented s_load_dword per m (4B-aligned k0=7*q slices) + lgkmcnt
//     mixing with ds_read; 5.0M LDS bank-conflict cycles (halo stride 10).
// R8: Wet rows padded to 128 (p*32+kk, kk<32): wave slice k0=(g&3)*8 is
//     32B-aligned -> 1x s_load_dwordx8 per rs (9 per m). Halo [m][10][12]
//     (stride 12 -> every bank exactly 2 lanes = free). q=8 outputs/wave.
//
// ws layout (float offsets):
#define OFF_FEAT 0              // feat [b][m][4096]               1,048,576 f
#define OFF_WET  1048576        // W_enc^T [m*9+rs][p*32+kk]          73,728 f
#define OFF_WCT  1122304        // W_comp^T [c][m]                    16,384 f
#define OFF_WK   1138688        // wk2 [p*25+k][b*4096+pix]        1,638,400 f
#define WS_FLOATS 2777088       // = 11,108,352 bytes

// ---------------- prep: weight transposes ----------------
__global__ __launch_bounds__(256) void prep_kernel(
    const float* __restrict__ Wc, const float* __restrict__ We,
    float* __restrict__ ws) {
    int i = blockIdx.x * 256 + threadIdx.x;
    if (i < 16384) {                       // WcT[c*64+m] = Wc[m][c]
        int c = i >> 6, m = i & 63;
        ws[OFF_WCT + i] = Wc[m * 256 + c];
    }
    if (i < 73728) {                       // Wet[(m*9+rs)*128 + p*32 + kk]
        int mrs = i >> 7, rem = i & 127;
        int p = rem >> 5, kk = rem & 31;
        ws[OFF_WET + i] = (kk < 25) ? We[(p * 25 + kk) * 576 + mrs] : 0.f;
    }
}

// ---------------- K1: 1x1 compress conv + relu ----------------
// grid 1024 = 256 px-groups x 4 m-quarters. 256 thr = 64 lanes x 4 chunks(4 m).
// 4 staging phases of 64 ch (16 KB LDS) -> more blocks/CU than R5's 32 KB.
__global__ __launch_bounds__(256) void compress_kernel(
    const float* __restrict__ x, const float* __restrict__ bc,
    const float* __restrict__ ws, float* __restrict__ feat) {
    __shared__ float xs[64 * 64];          // 16 KB
    int blk = blockIdx.x;
    int pxg = blk >> 2, mq = blk & 3;
    int pixbase = pxg * 64;
    int b = pixbase >> 12, pl = pixbase & 4095;
    int lane = threadIdx.x & 63;
    int chunk = __builtin_amdgcn_readfirstlane(threadIdx.x >> 6);
    int m0 = mq * 16 + chunk * 4;          // wave-uniform
    const float* wct = ws + OFF_WCT;
    float acc[4];
#pragma unroll
    for (int q = 0; q < 4; q++) acc[q] = 0.f;
    for (int h = 0; h < 4; h++) {
        int ch0 = h << 6;
        for (int idx = threadIdx.x; idx < 64 * 64; idx += 256) {
            int c = idx >> 6, pp = idx & 63;
            xs[idx] = x[((b * 256 + ch0 + c) << 12) + pl + pp];
        }
        __syncthreads();
        for (int c = 0; c < 64; c++) {
            float xv = xs[(c << 6) + lane];
            const float* wr = wct + (ch0 + c) * 64 + m0;   // uniform -> s_load
#pragma unroll
            for (int q = 0; q < 4; q++) acc[q] += xv * wr[q];
        }
        __syncthreads();
    }
#pragma unroll
    for (int q = 0; q < 4; q++) {
        int m = m0 + q;
        float v = acc[q] + bc[m];
        feat[(b * 64 + m) * 4096 + pl + lane] = v > 0.f ? v : 0.f;
    }
}

// ---------------- K2: 3x3 enc conv + bias + softmax(25) ----------------
// grid 256 (b x 8x8 tile), 1024 thr = 64 px x (4 p x 4 k-eighths), q=8.
// Weights: 1x s_load_dwordx8 per rs (32B-aligned uniform slice).
// 16 waves/block, 1 block/CU -> 4 waves/SIMD.
__global__ __launch_bounds__(1024) void enc_kernel(
    const float* __restrict__ be, const float* __restrict__ ws,
    float* __restrict__ wkout) {
    __shared__ float fs[7680];             // feat halo [m][10][12] / later logits [px][100]
    int t = threadIdx.x;
    int blk = blockIdx.x;
    int b = blk >> 6, tile = blk & 63;
    int i0 = (tile >> 3) << 3, j0 = (tile & 7) << 3;
    int pix = t & 63;
    int li = pix >> 3, lj = pix & 7;
    int g = __builtin_amdgcn_readfirstlane(t >> 6);  // 0..15, wave-uniform
    int p = g >> 2, k0 = (g & 3) << 3;               // kk = k0 + q, q<8 (pad >=25)
    const float* feat = ws + OFF_FEAT;
    const float* wet = ws + OFF_WET + p * 32 + k0;   // uniform, 32B-aligned

    for (int idx = t; idx < 6400; idx += 1024) {     // stage feat halo (0-padded)
        int m = idx / 100, pos = idx - m * 100;
        int r = pos / 10, s = pos - r * 10;
        int gi = i0 + r - 1, gj = j0 + s - 1;
        float v = 0.f;
        if ((unsigned)gi < 64u && (unsigned)gj < 64u)
            v = feat[(b * 64 + m) * 4096 + (gi << 6) + gj];
        fs[m * 120 + r * 12 + s] = v;                // stride-12 rows: conflict-free
    }
    __syncthreads();

    float acc[8];
#pragma unroll
    for (int q = 0; q < 8; q++) acc[q] = 0.f;

#pragma unroll 2
    for (int m = 0; m < 64; m++) {
        const float* fb = fs + m * 120 + li * 12 + lj;
        float f9[9];
#pragma unroll
        for (int r = 0; r < 3; r++)
#pragma unroll
            for (int s = 0; s < 3; s++) f9[r * 3 + s] = fb[r * 12 + s];
        const float* wrow = wet + m * 1152;          // uniform -> s_load_dwordx8
#pragma unroll
        for (int rs = 0; rs < 9; rs++) {
            float f = f9[rs];
            const float* wr = wrow + rs * 128;
#pragma unroll
            for (int q = 0; q < 8; q++) acc[q] += f * wr[q];
        }
    }
    __syncthreads();                                 // halo reads done

    // logits (+bias) -> fs[pix*100 + p*25 + kk] (kk>=25 is pad, skip)
#pragma unroll
    for (int q = 0; q < 8; q++) {
        int k = k0 + q;
        if (k < 25) fs[pix * 100 + p * 25 + k] = acc[q] + be[p * 25 + k];
    }
    __syncthreads();

    if (t < 256) {                                   // softmax: thread = (pix, p)
        int sp = t >> 6, spx = t & 63;
        const float* lg = fs + spx * 100 + sp * 25;
        float sv[25], mx = -1e30f;
#pragma unroll
        for (int k = 0; k < 25; k++) { sv[k] = lg[k]; mx = fmaxf(mx, sv[k]); }
        float s = 0.f;
#pragma unroll
        for (int k = 0; k < 25; k++) { sv[k] = __expf(sv[k] - mx); s += sv[k]; }
        float inv = 1.f / s;
        int pgl = ((i0 + (spx >> 3)) << 6) + j0 + (spx & 7);
        float* wp = wkout + (sp * 25) * 16384 + (b << 12) + pgl;
#pragma unroll
        for (int k = 0; k < 25; k++) wp[k * 16384] = sv[k] * inv;  // coalesced
    }
}

// ---------------- K3: gather + pixel rearrange ----------------
// grid 4096 = (b*64+i)*16 + cc(16 ch). 256 thr = 64 j x (2 p-pairs x 2 c-halves).
// LDS 21.8 KB -> 7 blocks/CU (28 waves) vs R5's 3 (12 waves).
__global__ __launch_bounds__(256) void gather_kernel(
    const float* __restrict__ x, const float* __restrict__ ws,
    float* __restrict__ out) {
    __shared__ float xs[16 * 5 * 68];                // 21.76 KB
    int t = threadIdx.x;
    int blk = blockIdx.x;
    int cc = blk & 15;
    int bi = blk >> 4;
    int b = bi >> 6, i = bi & 63;
    int j = t & 63;
    int g = t >> 6;
    int ph = g >> 1, ch = g & 1;

    // coalesced wk loads: wk2[(p*25+k)*16384 + b*4096 + i*64 + j]
    float w0[25], w1[25];
    {
        const float* wp = ws + OFF_WK + (ph * 50) * 16384 + (b << 12) + (i << 6) + j;
#pragma unroll
        for (int k = 0; k < 25; k++) {
            w0[k] = wp[k * 16384];
            w1[k] = wp[(25 + k) * 16384];
        }
    }

    // div-free-ish staging: aligned 64-float row core + guarded zero pads.
    {
        int lane = t & 63, cd0 = t >> 6;             // (c,dy) pairs, 4 at a time
        for (int cd = cd0; cd < 80; cd += 4) {
            int c = cd / 5, dy = cd - c * 5;
            int gi = i - 2 + dy;
            float v = 0.f;
            if ((unsigned)gi < 64u)
                v = x[((b * 256 + (cc << 4) + c) << 12) + (gi << 6) + lane];
            float* row = xs + cd * 68;
            row[2 + lane] = v;
            if (lane < 2) row[lane] = 0.f;           // gj < 0 pad
            if (lane >= 62) row[lane + 4] = 0.f;     // gj >= 64 pad
        }
    }
    __syncthreads();

    for (int c2 = ch; c2 < 16; c2 += 2) {
        const float* xb = xs + (c2 * 5) * 68 + j;    // u = j+dx -> gj = j+dx-2
        float a0 = 0.f, a1 = 0.f;
#pragma unroll
        for (int dy = 0; dy < 5; dy++) {
#pragma unroll
            for (int dx = 0; dx < 5; dx++) {
                float xv = xb[dy * 68 + dx];
                int k = dy * 5 + dx;
                a0 += xv * w0[k];
                a1 += xv * w1[k];
            }
        }
        int c = (cc << 4) + c2;
        float2 o2 = make_float2(a0, a1);
        *(float2*)(out + (((b * 256 + c) << 12) + (i << 6) + j) * 4 + ph * 2) = o2;
    }
}

// ---------------- fallback: round-3 fused kernel (correct, slow) ----------------
__global__ __launch_bounds__(512) void carafe_fused(
    const float* __restrict__ x, const float* __restrict__ Wc,
    const float* __restrict__ bc, const float* __restrict__ We,
    const float* __restrict__ be, float* __restrict__ out) {
    __shared__ float xs[32 * 144];
    __shared__ float fw[6656];
    __shared__ float wst[3600];
    const int t = threadIdx.x;
    const int blk = blockIdx.x;
    const int b = blk >> 6, tile = blk & 63;
    const int i0 = (tile >> 3) << 3, j0 = (tile & 7) << 3;
    const int wid = t >> 6, pix = t & 63;
    const int li = pix >> 3, lj = pix & 7;
    float facc[13];
#pragma unroll
    for (int q = 0; q < 13; q++) facc[q] = 0.f;
    for (int cc = 0; cc < 8; cc++) {
        for (int idx = t; idx < 32 * 144; idx += 512) {
            int c = idx / 144, pos = idx - c * 144;
            int r = pos / 12, u = pos - r * 12;
            int gi = i0 + r - 2, gj = j0 + u - 2;
            float v = 0.f;
            if ((unsigned)gi < 64u && (unsigned)gj < 64u)
                v = x[(((b * 256 + cc * 32 + c) << 12) + (gi << 6) + gj)];
            xs[idx] = v;
        }
        __syncthreads();
#pragma unroll
        for (int q = 0; q < 13; q++) {
            int idx = q * 512 + t;
            if (idx < 6400) {
                int m = idx / 100, pos = idx - m * 100;
                int fi = pos / 10, fj = pos - fi * 10;
                int tp = (fi + 1) * 12 + fj + 1;
                const float* wr = Wc + m * 256 + cc * 32;
                float a = facc[q];
                for (int c = 0; c < 32; c++) a += xs[c * 144 + tp] * wr[c];
                facc[q] = a;
            }
        }
        __syncthreads();
    }
#pragma unroll
    for (int q = 0; q < 13; q++) {
        int idx = q * 512 + t;
        if (idx < 6400) {
            int m = idx / 100, pos = idx - m * 100;
            int fi = pos / 10, fj = pos - fi * 10;
            int gi = i0 + fi - 1, gj = j0 + fj - 1;
            float v = facc[q] + bc[m];
            v = v > 0.f ? v : 0.f;
            if ((unsigned)gi >= 64u || (unsigned)gj >= 64u) v = 0.f;
            fw[idx] = v;
        }
    }
    float acc[13];
#pragma unroll
    for (int q = 0; q < 13; q++) acc[q] = 0.f;
    for (int mb = 0; mb < 16; mb++) {
        for (int idx = t; idx < 3600; idx += 512) {
            int mm = idx / 900, rem = idx - mm * 900;
            int o = rem / 9, rs = rem - o * 9;
            wst[idx] = We[o * 576 + (mb * 4 + mm) * 9 + rs];
        }
        __syncthreads();
#pragma unroll
        for (int mm = 0; mm < 4; mm++) {
            const float* fb = fw + (mb * 4 + mm) * 100 + li * 10 + lj;
            float f9[9];
#pragma unroll
            for (int r = 0; r < 3; r++)
#pragma unroll
                for (int s = 0; s < 3; s++) f9[r * 3 + s] = fb[r * 10 + s];
#pragma unroll
            for (int q = 0; q < 13; q++) {
                int o = q * 8 + wid;
                if (o < 100) {
                    const float* wr = wst + mm * 900 + o * 9;
                    float a = acc[q];
#pragma unroll
                    for (int rs = 0; rs < 9; rs++) a += f9[rs] * wr[rs];
                    acc[q] = a;
                }
            }
        }
        __syncthreads();
    }
#pragma unroll
    for (int q = 0; q < 13; q++) {
        int o = q * 8 + wid;
        if (o < 100) fw[pix * 104 + o] = acc[q];
    }
    __syncthreads();
    float sv[25];
    float inv = 0.f;
    const int sp = t >> 6, spx = t & 63;
    const bool act = (t < 256);
    if (act) {
        float mx = -1e30f;
#pragma unroll
        for (int k = 0; k < 25; k++) {
            sv[k] = fw[spx * 104 + sp * 25 + k] + be[sp * 25 + k];
            mx = fmaxf(mx, sv[k]);
        }
        float s = 0.f;
#pragma unroll
        for (int k = 0; k < 25; k++) { sv[k] = __expf(sv[k] - mx); s += sv[k]; }
        inv = 1.f / s;
    }
    __syncthreads();
    if (act) {
#pragma unroll
        for (int k = 0; k < 25; k++) fw[spx * 104 + k * 4 + sp] = sv[k] * inv;
    }
    __syncthreads();
    float w[25][4];
    const float4* wp = (const float4*)(fw + pix * 104);
#pragma unroll
    for (int k = 0; k < 25; k++) {
        float4 ww = wp[k];
        w[k][0] = ww.x; w[k][1] = ww.y; w[k][2] = ww.z; w[k][3] = ww.w;
    }
    const int pgl = ((i0 + li) << 6) + (j0 + lj);
    for (int cc = 0; cc < 8; cc++) {
        for (int idx = t; idx < 32 * 144; idx += 512) {
            int c = idx / 144, pos = idx - c * 144;
            int r = pos / 12, u = pos - r * 12;
            int gi = i0 + r - 2, gj = j0 + u - 2;
            float v = 0.f;
            if ((unsigned)gi < 64u && (unsigned)gj < 64u)
                v = x[(((b * 256 + cc * 32 + c) << 12) + (gi << 6) + gj)];
            xs[idx] = v;
        }
        __syncthreads();
        for (int c8 = wid; c8 < 32; c8 += 8) {
            const float* xc = xs + c8 * 144 + li * 12 + lj;
            float a0 = 0.f, a1 = 0.f, a2 = 0.f, a3 = 0.f;
#pragma unroll
            for (int dy = 0; dy < 5; dy++) {
#pragma unroll
                for (int dx = 0; dx < 5; dx++) {
                    float xv = xc[dy * 12 + dx];
                    const int k = dy * 5 + dx;
                    a0 += xv * w[k][0];
                    a1 += xv * w[k][1];
                    a2 += xv * w[k][2];
                    a3 += xv * w[k][3];
                }
            }
            int c = cc * 32 + c8;
            float4 o4 = make_float4(a0, a1, a2, a3);
            *(float4*)(out + (((long long)(b * 256 + c)) << 14) + pgl * 4) = o4;
        }
        __syncthreads();
    }
}

extern "C" void kernel_launch(void* const* d_in, const int* in_sizes, int n_in,
                              void* d_out, int out_size, void* d_ws, size_t ws_size,
                              hipStream_t stream) {
    const float* x  = (const float*)d_in[0];
    const float* Wc = (const float*)d_in[1];
    const float* bc = (const float*)d_in[2];
    const float* We = (const float*)d_in[3];
    const float* be = (const float*)d_in[4];
    float* out = (float*)d_out;

    if (ws_size >= (size_t)WS_FLOATS * sizeof(float)) {
        float* ws = (float*)d_ws;
        prep_kernel<<<288, 256, 0, stream>>>(Wc, We, ws);
        compress_kernel<<<1024, 256, 0, stream>>>(x, bc, ws, ws + OFF_FEAT);
        enc_kernel<<<256, 1024, 0, stream>>>(be, ws, ws + OFF_WK);
        gather_kernel<<<4096, 256, 0, stream>>>(x, ws, out);
    } else {
        carafe_fused<<<256, 512, 0, stream>>>(x, Wc, bc, We, be, out);
    }
}

// Round 4
// 191.333 us; speedup vs baseline: 1.0427x; 1.0070x over previous
//
#include <hip/hip_runtime.h>

// CARAFE++ (B=4, C=256, H=W=64, SCALE=2, K=5, G=1, MID=64, ENC_OUT=100). FP32 I/O.
// R8: 192.7us; enc 52.9us @ 47% VALUBusy, 38% occ -> grid-capped at 16 waves/CU.
// R9: enc split by (tile,p): grid 1024 x 512thr, 8 waves x q=4 (s_load_dwordx4),
//     two-phase 32-m halo staging (LDS 15.4KB) -> 4 blocks/CU = 32 waves/CU.
//     Softmax stays block-local (p is an output dim). No new ws memory.
// R10: resubmit of R9 — round-3 bench was an infra failure (container died
//     twice, no profile); code re-audited for OOB/launch_bounds issues: clean.
//
// ws layout (float offsets):
#define OFF_FEAT 0              // feat [b][m][4096]               1,048,576 f
#define OFF_WET  1048576        // W_enc^T [m*9+rs][p*32+kk]          73,728 f
#define OFF_WCT  1122304        // W_comp^T [c][m]                    16,384 f
#define OFF_WK   1138688        // wk2 [p*25+k][b*4096+pix]        1,638,400 f
#define WS_FLOATS 2777088       // = 11,108,352 bytes

// ---------------- prep: weight transposes ----------------
__global__ __launch_bounds__(256) void prep_kernel(
    const float* __restrict__ Wc, const float* __restrict__ We,
    float* __restrict__ ws) {
    int i = blockIdx.x * 256 + threadIdx.x;
    if (i < 16384) {                       // WcT[c*64+m] = Wc[m][c]
        int c = i >> 6, m = i & 63;
        ws[OFF_WCT + i] = Wc[m * 256 + c];
    }
    if (i < 73728) {                       // Wet[(m*9+rs)*128 + p*32 + kk]
        int mrs = i >> 7, rem = i & 127;
        int p = rem >> 5, kk = rem & 31;
        ws[OFF_WET + i] = (kk < 25) ? We[(p * 25 + kk) * 576 + mrs] : 0.f;
    }
}

// ---------------- K1: 1x1 compress conv + relu ----------------
// grid 1024 = 256 px-groups x 4 m-quarters. 256 thr = 64 lanes x 4 chunks(4 m).
__global__ __launch_bounds__(256) void compress_kernel(
    const float* __restrict__ x, const float* __restrict__ bc,
    const float* __restrict__ ws, float* __restrict__ feat) {
    __shared__ float xs[64 * 64];          // 16 KB
    int blk = blockIdx.x;
    int pxg = blk >> 2, mq = blk & 3;
    int pixbase = pxg * 64;
    int b = pixbase >> 12, pl = pixbase & 4095;
    int lane = threadIdx.x & 63;
    int chunk = __builtin_amdgcn_readfirstlane(threadIdx.x >> 6);
    int m0 = mq * 16 + chunk * 4;          // wave-uniform
    const float* wct = ws + OFF_WCT;
    float acc[4];
#pragma unroll
    for (int q = 0; q < 4; q++) acc[q] = 0.f;
    for (int h = 0; h < 4; h++) {
        int ch0 = h << 6;
        for (int idx = threadIdx.x; idx < 64 * 64; idx += 256) {
            int c = idx >> 6, pp = idx & 63;
            xs[idx] = x[((b * 256 + ch0 + c) << 12) + pl + pp];
        }
        __syncthreads();
        for (int c = 0; c < 64; c++) {
            float xv = xs[(c << 6) + lane];
            const float* wr = wct + (ch0 + c) * 64 + m0;   // uniform -> s_load
#pragma unroll
            for (int q = 0; q < 4; q++) acc[q] += xv * wr[q];
        }
        __syncthreads();
    }
#pragma unroll
    for (int q = 0; q < 4; q++) {
        int m = m0 + q;
        float v = acc[q] + bc[m];
        feat[(b * 64 + m) * 4096 + pl + lane] = v > 0.f ? v : 0.f;
    }
}

// ---------------- K2: 3x3 enc conv + bias + softmax(25) ----------------
// grid 1024 = (b x 8x8 tile) x 4 p. 512 thr = 64 px x 8 k-quarters (q=4).
// Two-phase 32-m halo staging: LDS 15.4KB -> 4 blocks/CU = 32 waves/CU.
// Weights: 1x s_load_dwordx4 per rs (16B-aligned uniform slice).
__global__ __launch_bounds__(512, 8) void enc_kernel(
    const float* __restrict__ be, const float* __restrict__ ws,
    float* __restrict__ wkout) {
    __shared__ float fs[3840];             // halo [32m][10][12] / logits [64px][33]
    int t = threadIdx.x;
    int blk = blockIdx.x;
    int tile = blk >> 2, p = blk & 3;
    int b = tile >> 6, t6 = tile & 63;
    int i0 = (t6 >> 3) << 3, j0 = (t6 & 7) << 3;
    int pix = t & 63;
    int li = pix >> 3, lj = pix & 7;
    int g = __builtin_amdgcn_readfirstlane(t >> 6);  // 0..7, wave-uniform
    int k0 = g << 2;                                 // kk = k0 + q, q<4 (pad >=25)
    const float* feat = ws + OFF_FEAT;
    const float* wet = ws + OFF_WET + p * 32 + k0;   // uniform, 16B-aligned

    float acc[4];
#pragma unroll
    for (int q = 0; q < 4; q++) acc[q] = 0.f;

    for (int ph = 0; ph < 2; ph++) {
        int mb = ph << 5;
        for (int idx = t; idx < 3200; idx += 512) {  // stage 32-m halo (0-padded)
            int m = idx / 100, pos = idx - m * 100;
            int r = pos / 10, s = pos - r * 10;
            int gi = i0 + r - 1, gj = j0 + s - 1;
            float v = 0.f;
            if ((unsigned)gi < 64u && (unsigned)gj < 64u)
                v = feat[(b * 64 + mb + m) * 4096 + (gi << 6) + gj];
            fs[m * 120 + r * 12 + s] = v;            // stride-12 rows
        }
        __syncthreads();

#pragma unroll 2
        for (int m = 0; m < 32; m++) {
            const float* fb = fs + m * 120 + li * 12 + lj;
            float f9[9];
#pragma unroll
            for (int r = 0; r < 3; r++)
#pragma unroll
                for (int s = 0; s < 3; s++) f9[r * 3 + s] = fb[r * 12 + s];
            const float* wrow = wet + (mb + m) * 1152;   // uniform -> s_load_dwordx4
#pragma unroll
            for (int rs = 0; rs < 9; rs++) {
                float f = f9[rs];
                const float* wr = wrow + rs * 128;
#pragma unroll
                for (int q = 0; q < 4; q++) acc[q] += f * wr[q];
            }
        }
        __syncthreads();                             // reads done before re-stage
    }

    // logits (+bias) -> fs[pix*33 + kk] (kk>=25 pad skipped; stride 33 = 2-way)
#pragma unroll
    for (int q = 0; q < 4; q++) {
        int k = k0 + q;
        if (k < 25) fs[pix * 33 + k] = acc[q] + be[p * 25 + k];
    }
    __syncthreads();

    if (t < 64) {                                    // softmax: thread = pixel
        const float* lg = fs + t * 33;
        float sv[25], mx = -1e30f;
#pragma unroll
        for (int k = 0; k < 25; k++) { sv[k] = lg[k]; mx = fmaxf(mx, sv[k]); }
        float s = 0.f;
#pragma unroll
        for (int k = 0; k < 25; k++) { sv[k] = __expf(sv[k] - mx); s += sv[k]; }
        float inv = 1.f / s;
        int pgl = ((i0 + (t >> 3)) << 6) + j0 + (t & 7);
        float* wp = wkout + (p * 25) * 16384 + (b << 12) + pgl;
#pragma unroll
        for (int k = 0; k < 25; k++) wp[k * 16384] = sv[k] * inv;  // coalesced
    }
}

// ---------------- K3: gather + pixel rearrange ----------------
// grid 4096 = (b*64+i)*16 + cc(16 ch). 256 thr = 64 j x (2 p-pairs x 2 c-halves).
__global__ __launch_bounds__(256) void gather_kernel(
    const float* __restrict__ x, const float* __restrict__ ws,
    float* __restrict__ out) {
    __shared__ float xs[16 * 5 * 68];                // 21.76 KB
    int t = threadIdx.x;
    int blk = blockIdx.x;
    int cc = blk & 15;
    int bi = blk >> 4;
    int b = bi >> 6, i = bi & 63;
    int j = t & 63;
    int g = t >> 6;
    int ph = g >> 1, ch = g & 1;

    // coalesced wk loads: wk2[(p*25+k)*16384 + b*4096 + i*64 + j]
    float w0[25], w1[25];
    {
        const float* wp = ws + OFF_WK + (ph * 50) * 16384 + (b << 12) + (i << 6) + j;
#pragma unroll
        for (int k = 0; k < 25; k++) {
            w0[k] = wp[k * 16384];
            w1[k] = wp[(25 + k) * 16384];
        }
    }

    // div-free-ish staging: aligned 64-float row core + guarded zero pads.
    {
        int lane = t & 63, cd0 = t >> 6;             // (c,dy) pairs, 4 at a time
        for (int cd = cd0; cd < 80; cd += 4) {
            int c = cd / 5, dy = cd - c * 5;
            int gi = i - 2 + dy;
            float v = 0.f;
            if ((unsigned)gi < 64u)
                v = x[((b * 256 + (cc << 4) + c) << 12) + (gi << 6) + lane];
            float* row = xs + cd * 68;
            row[2 + lane] = v;
            if (lane < 2) row[lane] = 0.f;           // gj < 0 pad
            if (lane >= 62) row[lane + 4] = 0.f;     // gj >= 64 pad
        }
    }
    __syncthreads();

    for (int c2 = ch; c2 < 16; c2 += 2) {
        const float* xb = xs + (c2 * 5) * 68 + j;    // u = j+dx -> gj = j+dx-2
        float a0 = 0.f, a1 = 0.f;
#pragma unroll
        for (int dy = 0; dy < 5; dy++) {
#pragma unroll
            for (int dx = 0; dx < 5; dx++) {
                float xv = xb[dy * 68 + dx];
                int k = dy * 5 + dx;
                a0 += xv * w0[k];
                a1 += xv * w1[k];
            }
        }
        int c = (cc << 4) + c2;
        float2 o2 = make_float2(a0, a1);
        *(float2*)(out + (((b * 256 + c) << 12) + (i << 6) + j) * 4 + ph * 2) = o2;
    }
}

// ---------------- fallback: round-3 fused kernel (correct, slow) ----------------
__global__ __launch_bounds__(512) void carafe_fused(
    const float* __restrict__ x, const float* __restrict__ Wc,
    const float* __restrict__ bc, const float* __restrict__ We,
    const float* __restrict__ be, float* __restrict__ out) {
    __shared__ float xs[32 * 144];
    __shared__ float fw[6656];
    __shared__ float wst[3600];
    const int t = threadIdx.x;
    const int blk = blockIdx.x;
    const int b = blk >> 6, tile = blk & 63;
    const int i0 = (tile >> 3) << 3, j0 = (tile & 7) << 3;
    const int wid = t >> 6, pix = t & 63;
    const int li = pix >> 3, lj = pix & 7;
    float facc[13];
#pragma unroll
    for (int q = 0; q < 13; q++) facc[q] = 0.f;
    for (int cc = 0; cc < 8; cc++) {
        for (int idx = t; idx < 32 * 144; idx += 512) {
            int c = idx / 144, pos = idx - c * 144;
            int r = pos / 12, u = pos - r * 12;
            int gi = i0 + r - 2, gj = j0 + u - 2;
            float v = 0.f;
            if ((unsigned)gi < 64u && (unsigned)gj < 64u)
                v = x[(((b * 256 + cc * 32 + c) << 12) + (gi << 6) + gj)];
            xs[idx] = v;
        }
        __syncthreads();
#pragma unroll
        for (int q = 0; q < 13; q++) {
            int idx = q * 512 + t;
            if (idx < 6400) {
                int m = idx / 100, pos = idx - m * 100;
                int fi = pos / 10, fj = pos - fi * 10;
                int tp = (fi + 1) * 12 + fj + 1;
                const float* wr = Wc + m * 256 + cc * 32;
                float a = facc[q];
                for (int c = 0; c < 32; c++) a += xs[c * 144 + tp] * wr[c];
                facc[q] = a;
            }
        }
        __syncthreads();
    }
#pragma unroll
    for (int q = 0; q < 13; q++) {
        int idx = q * 512 + t;
        if (idx < 6400) {
            int m = idx / 100, pos = idx - m * 100;
            int fi = pos / 10, fj = pos - fi * 10;
            int gi = i0 + fi - 1, gj = j0 + fj - 1;
            float v = facc[q] + bc[m];
            v = v > 0.f ? v : 0.f;
            if ((unsigned)gi >= 64u || (unsigned)gj >= 64u) v = 0.f;
            fw[idx] = v;
        }
    }
    float acc[13];
#pragma unroll
    for (int q = 0; q < 13; q++) acc[q] = 0.f;
    for (int mb = 0; mb < 16; mb++) {
        for (int idx = t; idx < 3600; idx += 512) {
            int mm = idx / 900, rem = idx - mm * 900;
            int o = rem / 9, rs = rem - o * 9;
            wst[idx] = We[o * 576 + (mb * 4 + mm) * 9 + rs];
        }
        __syncthreads();
#pragma unroll
        for (int mm = 0; mm < 4; mm++) {
            const float* fb = fw + (mb * 4 + mm) * 100 + li * 10 + lj;
            float f9[9];
#pragma unroll
            for (int r = 0; r < 3; r++)
#pragma unroll
                for (int s = 0; s < 3; s++) f9[r * 3 + s] = fb[r * 10 + s];
#pragma unroll
            for (int q = 0; q < 13; q++) {
                int o = q * 8 + wid;
                if (o < 100) {
                    const float* wr = wst + mm * 900 + o * 9;
                    float a = acc[q];
#pragma unroll
                    for (int rs = 0; rs < 9; rs++) a += f9[rs] * wr[rs];
                    acc[q] = a;
                }
            }
        }
        __syncthreads();
    }
#pragma unroll
    for (int q = 0; q < 13; q++) {
        int o = q * 8 + wid;
        if (o < 100) fw[pix * 104 + o] = acc[q];
    }
    __syncthreads();
    float sv[25];
    float inv = 0.f;
    const int sp = t >> 6, spx = t & 63;
    const bool act = (t < 256);
    if (act) {
        float mx = -1e30f;
#pragma unroll
        for (int k = 0; k < 25; k++) {
            sv[k] = fw[spx * 104 + sp * 25 + k] + be[sp * 25 + k];
            mx = fmaxf(mx, sv[k]);
        }
        float s = 0.f;
#pragma unroll
        for (int k = 0; k < 25; k++) { sv[k] = __expf(sv[k] - mx); s += sv[k]; }
        inv = 1.f / s;
    }
    __syncthreads();
    if (act) {
#pragma unroll
        for (int k = 0; k < 25; k++) fw[spx * 104 + k * 4 + sp] = sv[k] * inv;
    }
    __syncthreads();
    float w[25][4];
    const float4* wp = (const float4*)(fw + pix * 104);
#pragma unroll
    for (int k = 0; k < 25; k++) {
        float4 ww = wp[k];
        w[k][0] = ww.x; w[k][1] = ww.y; w[k][2] = ww.z; w[k][3] = ww.w;
    }
    const int pgl = ((i0 + li) << 6) + (j0 + lj);
    for (int cc = 0; cc < 8; cc++) {
        for (int idx = t; idx < 32 * 144; idx += 512) {
            int c = idx / 144, pos = idx - c * 144;
            int r = pos / 12, u = pos - r * 12;
            int gi = i0 + r - 2, gj = j0 + u - 2;
            float v = 0.f;
            if ((unsigned)gi < 64u && (unsigned)gj < 64u)
                v = x[(((b * 256 + cc * 32 + c) << 12) + (gi << 6) + gj)];
            xs[idx] = v;
        }
        __syncthreads();
        for (int c8 = wid; c8 < 32; c8 += 8) {
            const float* xc = xs + c8 * 144 + li * 12 + lj;
            float a0 = 0.f, a1 = 0.f, a2 = 0.f, a3 = 0.f;
#pragma unroll
            for (int dy = 0; dy < 5; dy++) {
#pragma unroll
                for (int dx = 0; dx < 5; dx++) {
                    float xv = xc[dy * 12 + dx];
                    const int k = dy * 5 + dx;
                    a0 += xv * w[k][0];
                    a1 += xv * w[k][1];
                    a2 += xv * w[k][2];
                    a3 += xv * w[k][3];
                }
            }
            int c = cc * 32 + c8;
            float4 o4 = make_float4(a0, a1, a2, a3);
            *(float4*)(out + (((long long)(b * 256 + c)) << 14) + pgl * 4) = o4;
        }
        __syncthreads();
    }
}

extern "C" void kernel_launch(void* const* d_in, const int* in_sizes, int n_in,
                              void* d_out, int out_size, void* d_ws, size_t ws_size,
                              hipStream_t stream) {
    const float* x  = (const float*)d_in[0];
    const float* Wc = (const float*)d_in[1];
    const float* bc = (const float*)d_in[2];
    const float* We = (const float*)d_in[3];
    const float* be = (const float*)d_in[4];
    float* out = (float*)d_out;

    if (ws_size >= (size_t)WS_FLOATS * sizeof(float)) {
        float* ws = (float*)d_ws;
        prep_kernel<<<288, 256, 0, stream>>>(Wc, We, ws);
        compress_kernel<<<1024, 256, 0, stream>>>(x, bc, ws, ws + OFF_FEAT);
        enc_kernel<<<1024, 512, 0, stream>>>(be, ws, ws + OFF_WK);
        gather_kernel<<<4096, 256, 0, stream>>>(x, ws, out);
    } else {
        carafe_fused<<<256, 512, 0, stream>>>(x, Wc, bc, We, be, out);
    }
}

// Round 5
// 188.643 us; speedup vs baseline: 1.0575x; 1.0143x over previous
//
#include <hip/hip_runtime.h>

// CARAFE++ (B=4, C=256, H=W=64, SCALE=2, K=5, G=1, MID=64, ENC_OUT=100). FP32 I/O.
// R9/R10: 191us; enc 61.7us @ 62% occ, 67% VALU — REGRESSION vs R8's 52.9:
//   4-way p-split quadrupled f9 ds_reads (2.36M->4.72M wave-reads; 44us/CU of
//   LDS pipe) -> enc became LDS-issue-bound. Occupancy can't fix a full pipe.
// R11: p-PAIR split: grid 512 = 256 tiles x 2, 512thr = 8 waves = 2p x 4kg x q=8.
//   Keeps R8's read economy (9 ds_reads / 72 FMAs, ~22us pipe) AND gives
//   2 independent blocks/CU (16 waves, two barrier domains overlap).
//
// ws layout (float offsets):
#define OFF_FEAT 0              // feat [b][m][4096]               1,048,576 f
#define OFF_WET  1048576        // W_enc^T [m*9+rs][p*32+kk]          73,728 f
#define OFF_WCT  1122304        // W_comp^T [c][m]                    16,384 f
#define OFF_WK   1138688        // wk2 [p*25+k][b*4096+pix]        1,638,400 f
#define WS_FLOATS 2777088       // = 11,108,352 bytes

// ---------------- prep: weight transposes ----------------
__global__ __launch_bounds__(256) void prep_kernel(
    const float* __restrict__ Wc, const float* __restrict__ We,
    float* __restrict__ ws) {
    int i = blockIdx.x * 256 + threadIdx.x;
    if (i < 16384) {                       // WcT[c*64+m] = Wc[m][c]
        int c = i >> 6, m = i & 63;
        ws[OFF_WCT + i] = Wc[m * 256 + c];
    }
    if (i < 73728) {                       // Wet[(m*9+rs)*128 + p*32 + kk]
        int mrs = i >> 7, rem = i & 127;
        int p = rem >> 5, kk = rem & 31;
        ws[OFF_WET + i] = (kk < 25) ? We[(p * 25 + kk) * 576 + mrs] : 0.f;
    }
}

// ---------------- K1: 1x1 compress conv + relu ----------------
// grid 1024 = 256 px-groups x 4 m-quarters. 256 thr = 64 lanes x 4 chunks(4 m).
__global__ __launch_bounds__(256) void compress_kernel(
    const float* __restrict__ x, const float* __restrict__ bc,
    const float* __restrict__ ws, float* __restrict__ feat) {
    __shared__ float xs[64 * 64];          // 16 KB
    int blk = blockIdx.x;
    int pxg = blk >> 2, mq = blk & 3;
    int pixbase = pxg * 64;
    int b = pixbase >> 12, pl = pixbase & 4095;
    int lane = threadIdx.x & 63;
    int chunk = __builtin_amdgcn_readfirstlane(threadIdx.x >> 6);
    int m0 = mq * 16 + chunk * 4;          // wave-uniform
    const float* wct = ws + OFF_WCT;
    float acc[4];
#pragma unroll
    for (int q = 0; q < 4; q++) acc[q] = 0.f;
    for (int h = 0; h < 4; h++) {
        int ch0 = h << 6;
        for (int idx = threadIdx.x; idx < 64 * 64; idx += 256) {
            int c = idx >> 6, pp = idx & 63;
            xs[idx] = x[((b * 256 + ch0 + c) << 12) + pl + pp];
        }
        __syncthreads();
        for (int c = 0; c < 64; c++) {
            float xv = xs[(c << 6) + lane];
            const float* wr = wct + (ch0 + c) * 64 + m0;   // uniform -> s_load
#pragma unroll
            for (int q = 0; q < 4; q++) acc[q] += xv * wr[q];
        }
        __syncthreads();
    }
#pragma unroll
    for (int q = 0; q < 4; q++) {
        int m = m0 + q;
        float v = acc[q] + bc[m];
        feat[(b * 64 + m) * 4096 + pl + lane] = v > 0.f ? v : 0.f;
    }
}

// ---------------- K2: 3x3 enc conv + bias + softmax(25) ----------------
// grid 512 = (b x 8x8 tile) x 2 p-pairs. 512 thr = 64 px x (2p x 4 kg), q=8.
// Two-phase 32-m halo staging; LDS 16.9KB -> 2 blocks/CU = 16 waves/CU in two
// independent barrier domains. Weights: 1x s_load_dwordx8 per rs.
__global__ __launch_bounds__(512, 4) void enc_kernel(
    const float* __restrict__ be, const float* __restrict__ ws,
    float* __restrict__ wkout) {
    __shared__ float fs[4224];             // halo [32m][10][12]=3840 / logits [64px][2][33]
    int t = threadIdx.x;
    int blk = blockIdx.x;
    int tile = blk >> 1, ph2 = blk & 1;    // p-pair index
    int b = tile >> 6, t6 = tile & 63;
    int i0 = (t6 >> 3) << 3, j0 = (t6 & 7) << 3;
    int pix = t & 63;
    int li = pix >> 3, lj = pix & 7;
    int g = __builtin_amdgcn_readfirstlane(t >> 6);  // 0..7, wave-uniform
    int pp = g >> 2;                                 // p within pair
    int p = (ph2 << 1) | pp;
    int k0 = (g & 3) << 3;                           // kk = k0 + q, q<8 (pad >=25)
    const float* feat = ws + OFF_FEAT;
    const float* wet = ws + OFF_WET + p * 32 + k0;   // uniform, 32B-aligned

    float acc[8];
#pragma unroll
    for (int q = 0; q < 8; q++) acc[q] = 0.f;

    for (int phase = 0; phase < 2; phase++) {
        int mb = phase << 5;
        for (int idx = t; idx < 3200; idx += 512) {  // stage 32-m halo (0-padded)
            int m = idx / 100, pos = idx - m * 100;
            int r = pos / 10, s = pos - r * 10;
            int gi = i0 + r - 1, gj = j0 + s - 1;
            float v = 0.f;
            if ((unsigned)gi < 64u && (unsigned)gj < 64u)
                v = feat[(b * 64 + mb + m) * 4096 + (gi << 6) + gj];
            fs[m * 120 + r * 12 + s] = v;            // stride-12 rows (2-way = free)
        }
        __syncthreads();

#pragma unroll 2
        for (int m = 0; m < 32; m++) {
            const float* fb = fs + m * 120 + li * 12 + lj;
            float f9[9];
#pragma unroll
            for (int r = 0; r < 3; r++)
#pragma unroll
                for (int s = 0; s < 3; s++) f9[r * 3 + s] = fb[r * 12 + s];
            const float* wrow = wet + (mb + m) * 1152;   // uniform -> s_load_dwordx8
#pragma unroll
            for (int rs = 0; rs < 9; rs++) {
                float f = f9[rs];
                const float* wr = wrow + rs * 128;
#pragma unroll
                for (int q = 0; q < 8; q++) acc[q] += f * wr[q];
            }
        }
        __syncthreads();                             // reads done before re-stage
    }

    // logits (+bias) -> fs[pix*66 + pp*33 + kk] (kk>=25 pad skipped)
#pragma unroll
    for (int q = 0; q < 8; q++) {
        int k = k0 + q;
        if (k < 25) fs[pix * 66 + pp * 33 + k] = acc[q] + be[p * 25 + k];
    }
    __syncthreads();

    if (t < 128) {                                   // softmax: thread = (pp, pixel)
        int sp = t >> 6, spx = t & 63;
        const float* lg = fs + spx * 66 + sp * 33;
        float sv[25], mx = -1e30f;
#pragma unroll
        for (int k = 0; k < 25; k++) { sv[k] = lg[k]; mx = fmaxf(mx, sv[k]); }
        float s = 0.f;
#pragma unroll
        for (int k = 0; k < 25; k++) { sv[k] = __expf(sv[k] - mx); s += sv[k]; }
        float inv = 1.f / s;
        int preal = (ph2 << 1) | sp;
        int pgl = ((i0 + (spx >> 3)) << 6) + j0 + (spx & 7);
        float* wp = wkout + (preal * 25) * 16384 + (b << 12) + pgl;
#pragma unroll
        for (int k = 0; k < 25; k++) wp[k * 16384] = sv[k] * inv;  // coalesced
    }
}

// ---------------- K3: gather + pixel rearrange ----------------
// grid 4096 = (b*64+i)*16 + cc(16 ch). 256 thr = 64 j x (2 p-pairs x 2 c-halves).
__global__ __launch_bounds__(256) void gather_kernel(
    const float* __restrict__ x, const float* __restrict__ ws,
    float* __restrict__ out) {
    __shared__ float xs[16 * 5 * 68];                // 21.76 KB
    int t = threadIdx.x;
    int blk = blockIdx.x;
    int cc = blk & 15;
    int bi = blk >> 4;
    int b = bi >> 6, i = bi & 63;
    int j = t & 63;
    int g = t >> 6;
    int ph = g >> 1, ch = g & 1;

    // coalesced wk loads: wk2[(p*25+k)*16384 + b*4096 + i*64 + j]
    float w0[25], w1[25];
    {
        const float* wp = ws + OFF_WK + (ph * 50) * 16384 + (b << 12) + (i << 6) + j;
#pragma unroll
        for (int k = 0; k < 25; k++) {
            w0[k] = wp[k * 16384];
            w1[k] = wp[(25 + k) * 16384];
        }
    }

    // div-free-ish staging: aligned 64-float row core + guarded zero pads.
    {
        int lane = t & 63, cd0 = t >> 6;             // (c,dy) pairs, 4 at a time
        for (int cd = cd0; cd < 80; cd += 4) {
            int c = cd / 5, dy = cd - c * 5;
            int gi = i - 2 + dy;
            float v = 0.f;
            if ((unsigned)gi < 64u)
                v = x[((b * 256 + (cc << 4) + c) << 12) + (gi << 6) + lane];
            float* row = xs + cd * 68;
            row[2 + lane] = v;
            if (lane < 2) row[lane] = 0.f;           // gj < 0 pad
            if (lane >= 62) row[lane + 4] = 0.f;     // gj >= 64 pad
        }
    }
    __syncthreads();

    for (int c2 = ch; c2 < 16; c2 += 2) {
        const float* xb = xs + (c2 * 5) * 68 + j;    // u = j+dx -> gj = j+dx-2
        float a0 = 0.f, a1 = 0.f;
#pragma unroll
        for (int dy = 0; dy < 5; dy++) {
#pragma unroll
            for (int dx = 0; dx < 5; dx++) {
                float xv = xb[dy * 68 + dx];
                int k = dy * 5 + dx;
                a0 += xv * w0[k];
                a1 += xv * w1[k];
            }
        }
        int c = (cc << 4) + c2;
        float2 o2 = make_float2(a0, a1);
        *(float2*)(out + (((b * 256 + c) << 12) + (i << 6) + j) * 4 + ph * 2) = o2;
    }
}

// ---------------- fallback: round-3 fused kernel (correct, slow) ----------------
__global__ __launch_bounds__(512) void carafe_fused(
    const float* __restrict__ x, const float* __restrict__ Wc,
    const float* __restrict__ bc, const float* __restrict__ We,
    const float* __restrict__ be, float* __restrict__ out) {
    __shared__ float xs[32 * 144];
    __shared__ float fw[6656];
    __shared__ float wst[3600];
    const int t = threadIdx.x;
    const int blk = blockIdx.x;
    const int b = blk >> 6, tile = blk & 63;
    const int i0 = (tile >> 3) << 3, j0 = (tile & 7) << 3;
    const int wid = t >> 6, pix = t & 63;
    const int li = pix >> 3, lj = pix & 7;
    float facc[13];
#pragma unroll
    for (int q = 0; q < 13; q++) facc[q] = 0.f;
    for (int cc = 0; cc < 8; cc++) {
        for (int idx = t; idx < 32 * 144; idx += 512) {
            int c = idx / 144, pos = idx - c * 144;
            int r = pos / 12, u = pos - r * 12;
            int gi = i0 + r - 2, gj = j0 + u - 2;
            float v = 0.f;
            if ((unsigned)gi < 64u && (unsigned)gj < 64u)
                v = x[(((b * 256 + cc * 32 + c) << 12) + (gi << 6) + gj)];
            xs[idx] = v;
        }
        __syncthreads();
#pragma unroll
        for (int q = 0; q < 13; q++) {
            int idx = q * 512 + t;
            if (idx < 6400) {
                int m = idx / 100, pos = idx - m * 100;
                int fi = pos / 10, fj = pos - fi * 10;
                int tp = (fi + 1) * 12 + fj + 1;
                const float* wr = Wc + m * 256 + cc * 32;
                float a = facc[q];
                for (int c = 0; c < 32; c++) a += xs[c * 144 + tp] * wr[c];
                facc[q] = a;
            }
        }
        __syncthreads();
    }
#pragma unroll
    for (int q = 0; q < 13; q++) {
        int idx = q * 512 + t;
        if (idx < 6400) {
            int m = idx / 100, pos = idx - m * 100;
            int fi = pos / 10, fj = pos - fi * 10;
            int gi = i0 + fi - 1, gj = j0 + fj - 1;
            float v = facc[q] + bc[m];
            v = v > 0.f ? v : 0.f;
            if ((unsigned)gi >= 64u || (unsigned)gj >= 64u) v = 0.f;
            fw[idx] = v;
        }
    }
    float acc[13];
#pragma unroll
    for (int q = 0; q < 13; q++) acc[q] = 0.f;
    for (int mb = 0; mb < 16; mb++) {
        for (int idx = t; idx < 3600; idx += 512) {
            int mm = idx / 900, rem = idx - mm * 900;
            int o = rem / 9, rs = rem - o * 9;
            wst[idx] = We[o * 576 + (mb * 4 + mm) * 9 + rs];
        }
        __syncthreads();
#pragma unroll
        for (int mm = 0; mm < 4; mm++) {
            const float* fb = fw + (mb * 4 + mm) * 100 + li * 10 + lj;
            float f9[9];
#pragma unroll
            for (int r = 0; r < 3; r++)
#pragma unroll
                for (int s = 0; s < 3; s++) f9[r * 3 + s] = fb[r * 10 + s];
#pragma unroll
            for (int q = 0; q < 13; q++) {
                int o = q * 8 + wid;
                if (o < 100) {
                    const float* wr = wst + mm * 900 + o * 9;
                    float a = acc[q];
#pragma unroll
                    for (int rs = 0; rs < 9; rs++) a += f9[rs] * wr[rs];
                    acc[q] = a;
                }
            }
        }
        __syncthreads();
    }
#pragma unroll
    for (int q = 0; q < 13; q++) {
        int o = q * 8 + wid;
        if (o < 100) fw[pix * 104 + o] = acc[q];
    }
    __syncthreads();
    float sv[25];
    float inv = 0.f;
    const int sp = t >> 6, spx = t & 63;
    const bool act = (t < 256);
    if (act) {
        float mx = -1e30f;
#pragma unroll
        for (int k = 0; k < 25; k++) {
            sv[k] = fw[spx * 104 + sp * 25 + k] + be[sp * 25 + k];
            mx = fmaxf(mx, sv[k]);
        }
        float s = 0.f;
#pragma unroll
        for (int k = 0; k < 25; k++) { sv[k] = __expf(sv[k] - mx); s += sv[k]; }
        inv = 1.f / s;
    }
    __syncthreads();
    if (act) {
#pragma unroll
        for (int k = 0; k < 25; k++) fw[spx * 104 + k * 4 + sp] = sv[k] * inv;
    }
    __syncthreads();
    float w[25][4];
    const float4* wp = (const float4*)(fw + pix * 104);
#pragma unroll
    for (int k = 0; k < 25; k++) {
        float4 ww = wp[k];
        w[k][0] = ww.x; w[k][1] = ww.y; w[k][2] = ww.z; w[k][3] = ww.w;
    }
    const int pgl = ((i0 + li) << 6) + (j0 + lj);
    for (int cc = 0; cc < 8; cc++) {
        for (int idx = t; idx < 32 * 144; idx += 512) {
            int c = idx / 144, pos = idx - c * 144;
            int r = pos / 12, u = pos - r * 12;
            int gi = i0 + r - 2, gj = j0 + u - 2;
            float v = 0.f;
            if ((unsigned)gi < 64u && (unsigned)gj < 64u)
                v = x[(((b * 256 + cc * 32 + c) << 12) + (gi << 6) + gj)];
            xs[idx] = v;
        }
        __syncthreads();
        for (int c8 = wid; c8 < 32; c8 += 8) {
            const float* xc = xs + c8 * 144 + li * 12 + lj;
            float a0 = 0.f, a1 = 0.f, a2 = 0.f, a3 = 0.f;
#pragma unroll
            for (int dy = 0; dy < 5; dy++) {
#pragma unroll
                for (int dx = 0; dx < 5; dx++) {
                    float xv = xc[dy * 12 + dx];
                    const int k = dy * 5 + dx;
                    a0 += xv * w[k][0];
                    a1 += xv * w[k][1];
                    a2 += xv * w[k][2];
                    a3 += xv * w[k][3];
                }
            }
            int c = cc * 32 + c8;
            float4 o4 = make_float4(a0, a1, a2, a3);
            *(float4*)(out + (((long long)(b * 256 + c)) << 14) + pgl * 4) = o4;
        }
        __syncthreads();
    }
}

extern "C" void kernel_launch(void* const* d_in, const int* in_sizes, int n_in,
                              void* d_out, int out_size, void* d_ws, size_t ws_size,
                              hipStream_t stream) {
    const float* x  = (const float*)d_in[0];
    const float* Wc = (const float*)d_in[1];
    const float* bc = (const float*)d_in[2];
    const float* We = (const float*)d_in[3];
    const float* be = (const float*)d_in[4];
    float* out = (float*)d_out;

    if (ws_size >= (size_t)WS_FLOATS * sizeof(float)) {
        float* ws = (float*)d_ws;
        prep_kernel<<<288, 256, 0, stream>>>(Wc, We, ws);
        compress_kernel<<<1024, 256, 0, stream>>>(x, bc, ws, ws + OFF_FEAT);
        enc_kernel<<<512, 512, 0, stream>>>(be, ws, ws + OFF_WK);
        gather_kernel<<<4096, 256, 0, stream>>>(x, ws, out);
    } else {
        carafe_fused<<<256, 512, 0, stream>>>(x, Wc, bc, We, be, out);
    }
}